// Round 1
// baseline (15987.622 us; speedup 1.0000x reference)
//
#include <hip/hip_runtime.h>

// ---------------- problem constants ----------------
constexpr int SEQ = 2048;
constexpr int HD  = 512;     // H = D = DW
constexpr int TH3 = 1536;    // 3H
constexpr int ZT  = 3072;    // combined [W_hh | Ww_hh] output cols
constexpr int KWW = 3;

constexpr int GRID = 64;     // scan blocks
constexpr int NT   = 512;    // threads/block (8 waves)
constexpr int HB   = HD / GRID;   // 8 h-channels per block
constexpr int SPB  = SEQ / GRID;  // 32 steps/block metadata precompute
constexpr int MAXW = 16;
constexpr int ZWC  = TH3 / GRID;  // 24 word-z zeroing cols per block

// ws layout (bytes)
constexpr size_t WS_FLAGS  = 0;                     // 64 ints
constexpr size_t WS_CNT    = 1024;                  // dtype-detect counter
constexpr size_t WS_ZW     = 2048;                  // 3 x 1536 f32 word-z rotation
constexpr size_t WS_CS     = WS_ZW + 3*TH3*4;       // 2 x 512 f32 c ring
constexpr size_t WS_HR     = WS_CS + 2*HD*4;        // 2 x 512 f32 h ring
constexpr size_t WS_ZEROSZ = WS_HR + 2*HD*4;        // memset region end
constexpr size_t WS_CBUF   = ((WS_ZEROSZ + 255)/256)*256;          // 6144*512 f32
constexpr size_t WS_MHDR   = WS_CBUF + (size_t)SEQ*KWW*HD*4;       // 2048 i32
constexpr size_t WS_MROWS  = WS_MHDR + (size_t)SEQ*4;              // 2048*16 i32
constexpr size_t WS_WIB    = WS_MROWS + (size_t)SEQ*MAXW*4;        // 2048*1536 f32
constexpr size_t WS_AWIB   = WS_WIB  + (size_t)SEQ*TH3*4;          // 2048*512 f32
constexpr size_t WS_WWIB   = WS_AWIB + (size_t)SEQ*HD*4;           // 6144*1536 f32
constexpr size_t WS_WT     = WS_WWIB + (size_t)SEQ*KWW*TH3*4;      // 3072*512 f32 W^T
constexpr size_t WS_END    = WS_WT + (size_t)ZT*HD*4;

__device__ inline float bf2f(unsigned int u) {
    return __builtin_bit_cast(float, u << 16);
}
__device__ inline unsigned short f2bf(float f) {
    unsigned int u = __builtin_bit_cast(unsigned int, f);
    u += 0x7fffu + ((u >> 16) & 1u);   // RNE
    return (unsigned short)(u >> 16);
}
__device__ inline float sigf(float x) { return 1.0f / (1.0f + expf(-x)); }

// LLC-coherent (agent-scope relaxed) accesses: bypass non-coherent L1/L2.
template <typename T>
__device__ inline T ldg_a(const T* p) {
    return __hip_atomic_load((T*)p, __ATOMIC_RELAXED, __HIP_MEMORY_SCOPE_AGENT);
}
template <typename T>
__device__ inline void stg_a(T* p, T v) {
    __hip_atomic_store(p, v, __ATOMIC_RELAXED, __HIP_MEMORY_SCOPE_AGENT);
}

// dual-dtype loads: mode=1 -> bf16 storage, mode=0 -> f32 storage
__device__ inline float4 ld4e(const void* p, size_t eoff, int mode) {
    if (mode) {
        uint2 v = *(const uint2*)((const unsigned short*)p + eoff);
        return make_float4(bf2f(v.x & 0xffffu), bf2f(v.x >> 16),
                           bf2f(v.y & 0xffffu), bf2f(v.y >> 16));
    }
    return *(const float4*)((const float*)p + eoff);
}
__device__ inline float ld1e(const void* p, size_t eoff, int mode) {
    return mode ? bf2f((unsigned int)((const unsigned short*)p)[eoff])
                : ((const float*)p)[eoff];
}

// ---------------- dtype detection ----------------
constexpr int NDET = 4096;
__global__ void detect_kernel(const unsigned int* __restrict__ w, int* __restrict__ cnt) {
    int local = 0;
    for (int i = threadIdx.x; i < NDET; i += 256) {
        unsigned int e = (w[i] >> 7) & 0xffu;
        if (e >= 90u && e <= 140u) local++;
    }
    atomicAdd(cnt, local);
}

// ---------------- precompute GEMM: C[M,N] = gather(A)[M,K] @ B[K,N] + bias ----------------
template<bool GATHER>
__global__ __launch_bounds__(256) void gemm_bias_kernel(
    const void* __restrict__ A, const void* __restrict__ B,
    const void* __restrict__ bias, const int* __restrict__ ids,
    const int* __restrict__ cnt,
    float* __restrict__ C, int M, int N, int K)
{
    const int mode = (*cnt > NDET / 2) ? 1 : 0;
    __shared__ __align__(16) float As[16][68];
    __shared__ __align__(16) float Bs[16][68];
    const int tid = threadIdx.x;
    const int ty = tid >> 4, tx = tid & 15;
    const int m0 = blockIdx.y * 64, n0 = blockIdx.x * 64;
    const int lrow = tid >> 2;
    const int kq   = (tid & 3) * 4;
    const int arow = m0 + lrow;
    const size_t abase = (GATHER ? (size_t)ids[arow] : (size_t)arow) * (size_t)K;
    const int brow = tid >> 4;
    const int bc   = (tid & 15) * 4;
    const int bcol = n0 + bc;
    float acc[4][4] = {};
    for (int k0 = 0; k0 < K; k0 += 16) {
        float4 av = ld4e(A, abase + k0 + kq, mode);
        float4 bv = ld4e(B, (size_t)(k0 + brow) * N + bcol, mode);
        As[kq + 0][lrow] = av.x;
        As[kq + 1][lrow] = av.y;
        As[kq + 2][lrow] = av.z;
        As[kq + 3][lrow] = av.w;
        Bs[brow][bc + 0] = bv.x;
        Bs[brow][bc + 1] = bv.y;
        Bs[brow][bc + 2] = bv.z;
        Bs[brow][bc + 3] = bv.w;
        __syncthreads();
        #pragma unroll
        for (int kk = 0; kk < 16; ++kk) {
            float a[4], bb[4];
            #pragma unroll
            for (int u = 0; u < 4; ++u) a[u] = As[kk][ty * 4 + u];
            #pragma unroll
            for (int v = 0; v < 4; ++v) bb[v] = Bs[kk][tx * 4 + v];
            #pragma unroll
            for (int u = 0; u < 4; ++u)
                #pragma unroll
                for (int v = 0; v < 4; ++v)
                    acc[u][v] = fmaf(a[u], bb[v], acc[u][v]);
        }
        __syncthreads();
    }
    float4 bsv = ld4e(bias, (size_t)(n0 + tx * 4), mode);
    #pragma unroll
    for (int u = 0; u < 4; ++u) {
        float4 o;
        o.x = acc[u][0] + bsv.x; o.y = acc[u][1] + bsv.y;
        o.z = acc[u][2] + bsv.z; o.w = acc[u][3] + bsv.w;
        *(float4*)(C + (size_t)(m0 + ty * 4 + u) * N + n0 + tx * 4) = o;
    }
}

// ---------------- one-time transpose: WT[c][j] = [W_hh|Ww_hh][j][c] (f32 out) ----------------
__global__ __launch_bounds__(256) void transpose_cat_kernel(
    const void* __restrict__ W_hh, const void* __restrict__ Ww_hh,
    const int* __restrict__ cnt, float* __restrict__ out)
{
    const int mode = (*cnt > NDET / 2) ? 1 : 0;
    __shared__ float tile[32][33];
    const int c0 = blockIdx.x * 32;   // [0,3072)
    const int j0 = blockIdx.y * 32;   // [0,512)
    const int tx = threadIdx.x & 31, ty = threadIdx.x >> 5;
    const void* src = (c0 < TH3) ? W_hh : Ww_hh;
    const int cc0 = (c0 < TH3) ? c0 : c0 - TH3;
    #pragma unroll
    for (int dy = 0; dy < 32; dy += 8)
        tile[ty + dy][tx] = ld1e(src, (size_t)(j0 + ty + dy) * TH3 + cc0 + tx, mode);
    __syncthreads();
    #pragma unroll
    for (int dy = 0; dy < 32; dy += 8)
        out[(size_t)(c0 + ty + dy) * HD + j0 + tx] = tile[tx][ty + dy];
}

// ---------------- flag-array barrier (64 participants, no RMWs) ----------------
__device__ inline void gbar(int* flags, int b, int k) {
    __atomic_signal_fence(__ATOMIC_SEQ_CST);
    __builtin_amdgcn_s_waitcnt(0);       // drain this wave's stores/atomics
    __syncthreads();                     // all waves drained
    if (threadIdx.x < 64) {
        if (threadIdx.x == 0) stg_a(&flags[b], k);
        for (;;) {
            int v = ldg_a(&flags[threadIdx.x]);
            if (__all(v >= k)) break;
            __builtin_amdgcn_s_sleep(1);
        }
    }
    __syncthreads();
    __atomic_signal_fence(__ATOMIC_SEQ_CST);
}

__device__ inline float wave_red(float acc) {
    #pragma unroll
    for (int m = 1; m < 64; m <<= 1) acc += __shfl_xor(acc, m, 64);
    return acc;
}

// ---------------- persistent scan: column-local z, ONE barrier/step ----------------
__global__ __launch_bounds__(NT, 1) void lattice_scan(
    const float* __restrict__ WT, const void* __restrict__ Ww_hh,
    const void* __restrict__ aW_hh,
    const float* __restrict__ WIb, const float* __restrict__ AWIb,
    const float* __restrict__ WWIb,
    float* __restrict__ zw, float* __restrict__ csr, float* __restrict__ hring,
    float* __restrict__ c_buf, int* __restrict__ flags,
    const int* __restrict__ cnt,
    const int* __restrict__ gpos, const int* __restrict__ gslot,
    const unsigned char* __restrict__ gmaskb,
    int* __restrict__ meta_hdr, int* __restrict__ meta_rows,
    void* __restrict__ outp, int Km)
{
    __shared__ __align__(16) float Wa[HB][HD];       // own 8 cols of aW_hh (16 KB)
    __shared__ __align__(16) float cinS[MAXW][HD];   // staged cin rows (32 KB)
    __shared__ __align__(16) float zwFull[TH3];      // full word-z (len-2 steps)
    __shared__ __align__(16) float csFull[HD];       // full c_{t-1} (len-2 steps)
    __shared__ __align__(16) float hS[HD];           // full h_{t-1}
    __shared__ float zG[3][HB], wwOwn[KWW][3][HB], wiOwn[4][HB];
    __shared__ float hOwn[HB], cOwn[HB], wdot[MAXW][HB];
    __shared__ int mh_l[2], mr_l[2][MAXW];
    __shared__ int mfmt;

    const int b    = blockIdx.x;
    const int tid  = threadIdx.x;
    const int wid  = tid >> 6;
    const int q    = tid & 63;
    const int mode = (*cnt > NDET / 2) ? 1 : 0;
    const int hb0  = b * HB;          // first own h-channel

    // ---- one-time init: column-slice z weights into registers.
    // wave wid owns h-channel hb0+wid's 6 gate columns; lane q holds rows q+64i.
    float wreg[6][8];
    #pragma unroll
    for (int k = 0; k < 6; ++k)
        #pragma unroll
        for (int i = 0; i < 8; ++i)
            wreg[k][i] = WT[(size_t)(k * HD + hb0 + wid) * HD + q + 64 * i];
    // row-slice word-z weights (for pre-len2 publication): thread owns cols {tid,512+tid,1024+tid}
    float wwreg[8][3];
    #pragma unroll
    for (int j = 0; j < 8; ++j)
        #pragma unroll
        for (int g = 0; g < 3; ++g)
            wwreg[j][g] = ld1e(Ww_hh, (size_t)(hb0 + j) * TH3 + g * HD + tid, mode);
    for (int idx = tid; idx < HB * HD; idx += NT) {
        int ho = idx & (HB - 1), r = idx / HB;
        Wa[ho][r] = ld1e(aW_hh, (size_t)r * HD + hb0 + ho, mode);
    }
    if (tid < HB) { hOwn[tid] = 0.f; cOwn[tid] = 0.f; }
    if (tid == 0) mfmt = 0;
    __syncthreads();
    {   // mask storage width: nonzero byte at i%4!=0 => u8/bool storage
        int any = 0;
        int tot = SEQ * Km;
        for (int i = tid; i < tot; i += NT)
            if ((i & 3) && gmaskb[i]) any = 1;
        if (any) mfmt = 1;
    }
    __syncthreads();
    const int maskfmt = mfmt;
    const int* gmi = (const int*)gmaskb;

    // ---- one-time metadata precompute: rows packed (p<<2)|sl ----
    if (tid < SPB) {
        int t = b * SPB + tid;
        int nv = 0;
        for (int k = 0; k < Km; ++k) {
            int mv = maskfmt ? (int)gmaskb[t * Km + k] : gmi[t * Km + k];
            if (!mv) continue;
            int p = gpos[t * Km + k], sl = gslot[t * Km + k];
            if (p < 0 || p >= t || sl < 0 || sl >= KWW) continue;
            if (nv < MAXW) { stg_a(&meta_rows[t * MAXW + nv], (p << 2) | sl); nv++; }
        }
        stg_a(&meta_hdr[t], nv);
    }
    gbar(flags, b, 1);   // publish metadata

    // meta for step 0 (plain loads: immutable after barrier)
    if (tid == 0) mh_l[0] = ldg_a(&meta_hdr[0]);
    if (tid < MAXW) mr_l[0][tid] = ldg_a(&meta_rows[tid]);
    __syncthreads();

    for (int t = 0; t < SEQ; ++t) {
        const int par = t & 1;
        const int rd = t % 3, ad = (t + 1) % 3, zr = (t + 2) % 3;

        const int nv = mh_l[par];
        // any len-2 word (created at t-1, consumed this step)?
        bool anyl2 = false;
        for (int vi = 0; vi < nv; ++vi)
            if ((mr_l[par][vi] >> 2) == t - 1) anyl2 = true;

        // ===== window: batched loads -> LDS =====
        // full h_{t-1} (sc: written by all blocks last step)
        hS[tid] = ldg_a(&hring[((t + 1) & 1) * HD + tid]);
        // own WI/AWI rows (plain: immutable)
        if (tid < 4 * HB) {
            int g = tid >> 3, ho = tid & (HB - 1);
            wiOwn[g][ho] = (g < 3) ? WIb[(size_t)t * TH3 + g * HD + hb0 + ho]
                                   : AWIb[(size_t)t * HD + hb0 + ho];
        }
        // own WWI rows for cells born at t-1 (plain)
        if (t > 0 && tid < KWW * 3 * HB) {
            int sl = tid / (3 * HB), g = (tid / HB) % 3, ho = tid & (HB - 1);
            wwOwn[sl][g][ho] =
                WWIb[(size_t)((t - 1) * KWW + sl) * TH3 + g * HD + hb0 + ho];
        }
        // far cin rows -> cinS (plain float4: c_buf rows are write-once)
        {
            int g = tid >> 5, l = tid & 31;
            if (g < nv) {
                int e = mr_l[par][g], p = e >> 2, sl = e & 3;
                if (p <= t - 2) {
                    const float4* src =
                        (const float4*)(c_buf + (size_t)(p * KWW + sl) * HD);
                    float4* dst = (float4*)&cinS[g][0];
                    #pragma unroll
                    for (int i = 0; i < 4; ++i) dst[l + 32 * i] = src[l + 32 * i];
                }
            }
        }
        // len-2 support: full word-z (accumulated last step) + full c_{t-1}
        if (anyl2) {
            #pragma unroll
            for (int i = 0; i < 3; ++i)
                zwFull[tid + HD * i] = ldg_a(&zw[rd * TH3 + tid + HD * i]);
            csFull[tid] = ldg_a(&csr[((t + 1) & 1) * HD + tid]);
        }
        // prefetch next meta
        if (t + 1 < SEQ) {
            if (tid == 0) mh_l[par ^ 1] = ldg_a(&meta_hdr[t + 1]);
            if (tid < MAXW)
                mr_l[par ^ 1][tid] = ldg_a(&meta_rows[(size_t)(t + 1) * MAXW + tid]);
        }
        __syncthreads();

        // ===== column-local z GEMV + cells born at t-1 (per-wave, in-register) =====
        {
            float hv[8];
            #pragma unroll
            for (int i = 0; i < 8; ++i) hv[i] = hS[q + 64 * i];
            float zk[6];
            #pragma unroll
            for (int k = 0; k < 6; ++k) {
                float a = 0.f;
                #pragma unroll
                for (int i = 0; i < 8; ++i) a = fmaf(hv[i], wreg[k][i], a);
                zk[k] = wave_red(a);
            }
            if (q == 0) {
                zG[0][wid] = zk[0]; zG[1][wid] = zk[1]; zG[2][wid] = zk[2];
            }
            // born cells: word-z cols for own channel are zk[3..5] (all lanes hold sums)
            if (t > 0 && q < KWW) {
                float cv = sigf(wwOwn[q][0][wid] + zk[3]) * cOwn[wid]
                         + sigf(wwOwn[q][1][wid] + zk[4])
                           * tanhf(wwOwn[q][2][wid] + zk[5]);
                stg_a(&c_buf[(size_t)((t - 1) * KWW + q) * HD + hb0 + wid], cv);
            }
        }
        // ===== len-2 recompute: full cell into cinS[vi] =====
        if (anyl2) {
            for (int vi = 0; vi < nv; ++vi) {
                int e = mr_l[par][vi], p = e >> 2, sl = e & 3;
                if (p != t - 1) continue;
                const float* wrow = WWIb + (size_t)((t - 1) * KWW + sl) * TH3;
                cinS[vi][tid] = sigf(wrow[tid] + zwFull[tid]) * csFull[tid]
                              + sigf(wrow[HD + tid] + zwFull[HD + tid])
                                * tanhf(wrow[2 * HD + tid] + zwFull[2 * HD + tid]);
            }
        }
        __syncthreads();

        // ===== alpha dots: nv*8 wave-jobs, stride-64 conflict-free =====
        if (nv > 0) {
            for (int jj = wid; jj < nv * HB; jj += 8) {
                int vi = jj >> 3, ho = jj & (HB - 1);
                float acc = 0.f;
                #pragma unroll
                for (int i = 0; i < 8; ++i)
                    acc += cinS[vi][q + 64 * i] * Wa[ho][q + 64 * i];
                acc = wave_red(acc);
                if (q == 0) wdot[vi][ho] = acc;
            }
        }
        __syncthreads();

        // ===== merge: own 8 channels =====
        if (tid < HB) {
            int ho = tid;
            float gi = sigf(zG[0][ho] + wiOwn[0][ho]);
            float go = sigf(zG[1][ho] + wiOwn[1][ho]);
            float gg = tanhf(zG[2][ho] + wiOwn[2][ho]);
            float c1;
            if (nv > 0) {
                float wiE = expf(gi);
                float num = wiE * gg, den = wiE;
                for (int vi = 0; vi < nv; ++vi) {
                    float wa = expf(sigf(wiOwn[3][ho] + wdot[vi][ho]));
                    num += wa * cinS[vi][hb0 + ho];
                    den += wa;
                }
                c1 = num / den;
            } else {
                c1 = (1.f - gi) * cOwn[ho] + gi * gg;
            }
            float h1 = go * tanhf(c1);
            cOwn[ho] = c1;
            hOwn[ho] = h1;
            stg_a(&csr[par * HD + hb0 + ho], c1);
            stg_a(&hring[par * HD + hb0 + ho], h1);
            if (mode) {
                unsigned short* o = (unsigned short*)outp;
                o[(size_t)t * HD + hb0 + ho] = f2bf(h1);
                o[(size_t)SEQ * HD + (size_t)t * HD + hb0 + ho] = f2bf(c1);
            } else {
                float* o = (float*)outp;
                o[(size_t)t * HD + hb0 + ho] = h1;
                o[(size_t)SEQ * HD + (size_t)t * HD + hb0 + ho] = c1;
            }
        }
        __syncthreads();

        // ===== publish full word-z ONLY if next step consumes a len-2 word =====
        bool anyl2n = false;
        if (t + 1 < SEQ) {
            int nvn = mh_l[par ^ 1];
            for (int vi = 0; vi < nvn; ++vi)
                if ((mr_l[par ^ 1][vi] >> 2) == t) anyl2n = true;
        }
        if (anyl2n) {
            float h8[8];
            #pragma unroll
            for (int j = 0; j < 8; ++j) h8[j] = hOwn[j];
            #pragma unroll
            for (int g = 0; g < 3; ++g) {
                float p = 0.f;
                #pragma unroll
                for (int j = 0; j < 8; ++j) p = fmaf(h8[j], wwreg[j][g], p);
                atomicAdd(&zw[ad * TH3 + g * HD + tid], p);
            }
        }
        // zero rotation of word-z ring (own 24-col slice)
        if (tid < ZWC) stg_a(&zw[zr * TH3 + b * ZWC + tid], 0.f);

        // ===== single rendezvous =====
        gbar(flags, b, t + 2);
    }
}

extern "C" void kernel_launch(void* const* d_in, const int* in_sizes, int n_in,
                              void* d_out, int out_size, void* d_ws, size_t ws_size,
                              hipStream_t stream) {
    const void* x     = d_in[0];
    const void* W_ih  = d_in[1];
    const void* W_hh  = d_in[2];
    const void* bb    = d_in[3];
    const void* aW_ih = d_in[4];
    const void* aW_hh = d_in[5];
    const void* ab    = d_in[6];
    const void* Ww_ih = d_in[7];
    const void* Ww_hh = d_in[8];
    const void* bw    = d_in[9];
    const void* wemb  = d_in[10];
    const int* wids  = (const int*)d_in[11];
    const int* gpos  = (const int*)d_in[12];
    const int* gslot = (const int*)d_in[13];
    const unsigned char* gmask = (const unsigned char*)d_in[14];

    int Km = in_sizes[12] / SEQ;
    if (Km > 32) Km = 32;
    if (ws_size < WS_END) return;

    char* ws = (char*)d_ws;
    int*   flags = (int*)(ws + WS_FLAGS);
    int*   cnt   = (int*)(ws + WS_CNT);
    float* zw    = (float*)(ws + WS_ZW);
    float* csr   = (float*)(ws + WS_CS);
    float* hr    = (float*)(ws + WS_HR);
    float* c_buf = (float*)(ws + WS_CBUF);
    int*   mhdr  = (int*)(ws + WS_MHDR);
    int*   mrows = (int*)(ws + WS_MROWS);
    float* WIb   = (float*)(ws + WS_WIB);
    float* AWIb  = (float*)(ws + WS_AWIB);
    float* WWIb  = (float*)(ws + WS_WWIB);
    float* WT    = (float*)(ws + WS_WT);

    hipMemsetAsync(d_ws, 0, WS_ZEROSZ, stream);
    detect_kernel<<<1, 256, 0, stream>>>((const unsigned int*)W_ih, cnt);
    transpose_cat_kernel<<<dim3(ZT / 32, HD / 32), 256, 0, stream>>>(
        W_hh, Ww_hh, cnt, WT);
    gemm_bias_kernel<false><<<dim3(TH3 / 64, SEQ / 64), 256, 0, stream>>>(
        x, W_ih, bb, nullptr, cnt, WIb, SEQ, TH3, HD);
    gemm_bias_kernel<false><<<dim3(HD / 64, SEQ / 64), 256, 0, stream>>>(
        x, aW_ih, ab, nullptr, cnt, AWIb, SEQ, HD, HD);
    gemm_bias_kernel<true><<<dim3(TH3 / 64, (SEQ * KWW) / 64), 256, 0, stream>>>(
        wemb, Ww_ih, bw, wids, cnt, WWIb, SEQ * KWW, TH3, HD);
    lattice_scan<<<GRID, NT, 0, stream>>>(
        WT, Ww_hh, aW_hh, WIb, AWIb, WWIb,
        zw, csr, hr, c_buf, flags, cnt,
        gpos, gslot, gmask, mhdr, mrows, d_out, Km);
}

// Round 2
// 10628.372 us; speedup vs baseline: 1.5042x; 1.5042x over previous
//
#include <hip/hip_runtime.h>

// ---------------- problem constants ----------------
constexpr int SEQ = 2048;
constexpr int HD  = 512;     // H = D = DW
constexpr int TH3 = 1536;    // 3H
constexpr int ZT  = 3072;    // combined [W_hh | Ww_hh] output cols
constexpr int KWW = 3;

constexpr int GRID = 64;     // scan blocks
constexpr int NT   = 512;    // threads/block (8 waves)
constexpr int HB   = HD / GRID;   // 8 h-channels per block
constexpr int SPB  = SEQ / GRID;  // 32 steps/block metadata precompute
constexpr int MAXW = 16;

constexpr unsigned int SENT = 0xFFFFFFFFu;   // NaN bit pattern, unreachable by finite gate math

// ws layout (bytes)
// -- zero-memset region --
constexpr size_t WS_FLAGS  = 0;                         // 64 ints (init barrier only)
constexpr size_t WS_CNT    = 1024;                      // dtype-detect counter
constexpr size_t WS_ZWCNT  = 2048;                      // SEQ ints: word-z arrival counters
constexpr size_t WS_ZW     = WS_ZWCNT + (size_t)SEQ*4;  // SEQ x 1536 f32 word-z accumulators
constexpr size_t WS_ZEROSZ = WS_ZW + (size_t)SEQ*TH3*4;
// -- 0xFF-memset region (sentinel-polled buffers) --
constexpr size_t WS_CBUF   = ((WS_ZEROSZ + 255)/256)*256;        // SEQ*KWW*HD f32
constexpr size_t WS_HFULL  = WS_CBUF + (size_t)SEQ*KWW*HD*4;     // SEQ*HD f32 (h_t rows)
constexpr size_t WS_CFULL  = WS_HFULL + (size_t)SEQ*HD*4;        // SEQ*HD f32 (c_t rows)
constexpr size_t WS_FFEND  = WS_CFULL + (size_t)SEQ*HD*4;
// -- plain region --
constexpr size_t WS_MHDR   = ((WS_FFEND + 255)/256)*256;         // SEQ i32
constexpr size_t WS_MROWS  = WS_MHDR + (size_t)SEQ*4;            // SEQ*MAXW i32
constexpr size_t WS_WIB    = WS_MROWS + (size_t)SEQ*MAXW*4;      // SEQ*1536 f32
constexpr size_t WS_AWIB   = WS_WIB  + (size_t)SEQ*TH3*4;        // SEQ*512 f32
constexpr size_t WS_WWIB   = WS_AWIB + (size_t)SEQ*HD*4;         // SEQ*KWW*1536 f32
constexpr size_t WS_WT     = WS_WWIB + (size_t)SEQ*KWW*TH3*4;    // 3072*512 f32 W^T
constexpr size_t WS_END    = WS_WT + (size_t)ZT*HD*4;

__device__ inline float bf2f(unsigned int u) {
    return __builtin_bit_cast(float, u << 16);
}
__device__ inline unsigned short f2bf(float f) {
    unsigned int u = __builtin_bit_cast(unsigned int, f);
    u += 0x7fffu + ((u >> 16) & 1u);   // RNE
    return (unsigned short)(u >> 16);
}
__device__ inline float sigf(float x) { return 1.0f / (1.0f + expf(-x)); }

// LLC-coherent (agent-scope relaxed) accesses: bypass non-coherent L1/L2.
template <typename T>
__device__ inline T ldg_a(const T* p) {
    return __hip_atomic_load((T*)p, __ATOMIC_RELAXED, __HIP_MEMORY_SCOPE_AGENT);
}
template <typename T>
__device__ inline void stg_a(T* p, T v) {
    __hip_atomic_store(p, v, __ATOMIC_RELAXED, __HIP_MEMORY_SCOPE_AGENT);
}
__device__ inline unsigned int ldu_a(const unsigned int* p) {
    return __hip_atomic_load((unsigned int*)p, __ATOMIC_RELAXED, __HIP_MEMORY_SCOPE_AGENT);
}

// dual-dtype loads: mode=1 -> bf16 storage, mode=0 -> f32 storage
__device__ inline float4 ld4e(const void* p, size_t eoff, int mode) {
    if (mode) {
        uint2 v = *(const uint2*)((const unsigned short*)p + eoff);
        return make_float4(bf2f(v.x & 0xffffu), bf2f(v.x >> 16),
                           bf2f(v.y & 0xffffu), bf2f(v.y >> 16));
    }
    return *(const float4*)((const float*)p + eoff);
}
__device__ inline float ld1e(const void* p, size_t eoff, int mode) {
    return mode ? bf2f((unsigned int)((const unsigned short*)p)[eoff])
                : ((const float*)p)[eoff];
}

// ---------------- dtype detection ----------------
constexpr int NDET = 4096;
__global__ void detect_kernel(const unsigned int* __restrict__ w, int* __restrict__ cnt) {
    int local = 0;
    for (int i = threadIdx.x; i < NDET; i += 256) {
        unsigned int e = (w[i] >> 7) & 0xffu;
        if (e >= 90u && e <= 140u) local++;
    }
    atomicAdd(cnt, local);
}

// ---------------- precompute GEMM: C[M,N] = gather(A)[M,K] @ B[K,N] + bias ----------------
template<bool GATHER>
__global__ __launch_bounds__(256) void gemm_bias_kernel(
    const void* __restrict__ A, const void* __restrict__ B,
    const void* __restrict__ bias, const int* __restrict__ ids,
    const int* __restrict__ cnt,
    float* __restrict__ C, int M, int N, int K)
{
    const int mode = (*cnt > NDET / 2) ? 1 : 0;
    __shared__ __align__(16) float As[16][68];
    __shared__ __align__(16) float Bs[16][68];
    const int tid = threadIdx.x;
    const int ty = tid >> 4, tx = tid & 15;
    const int m0 = blockIdx.y * 64, n0 = blockIdx.x * 64;
    const int lrow = tid >> 2;
    const int kq   = (tid & 3) * 4;
    const int arow = m0 + lrow;
    const size_t abase = (GATHER ? (size_t)ids[arow] : (size_t)arow) * (size_t)K;
    const int brow = tid >> 4;
    const int bc   = (tid & 15) * 4;
    const int bcol = n0 + bc;
    float acc[4][4] = {};
    for (int k0 = 0; k0 < K; k0 += 16) {
        float4 av = ld4e(A, abase + k0 + kq, mode);
        float4 bv = ld4e(B, (size_t)(k0 + brow) * N + bcol, mode);
        As[kq + 0][lrow] = av.x;
        As[kq + 1][lrow] = av.y;
        As[kq + 2][lrow] = av.z;
        As[kq + 3][lrow] = av.w;
        Bs[brow][bc + 0] = bv.x;
        Bs[brow][bc + 1] = bv.y;
        Bs[brow][bc + 2] = bv.z;
        Bs[brow][bc + 3] = bv.w;
        __syncthreads();
        #pragma unroll
        for (int kk = 0; kk < 16; ++kk) {
            float a[4], bb[4];
            #pragma unroll
            for (int u = 0; u < 4; ++u) a[u] = As[kk][ty * 4 + u];
            #pragma unroll
            for (int v = 0; v < 4; ++v) bb[v] = Bs[kk][tx * 4 + v];
            #pragma unroll
            for (int u = 0; u < 4; ++u)
                #pragma unroll
                for (int v = 0; v < 4; ++v)
                    acc[u][v] = fmaf(a[u], bb[v], acc[u][v]);
        }
        __syncthreads();
    }
    float4 bsv = ld4e(bias, (size_t)(n0 + tx * 4), mode);
    #pragma unroll
    for (int u = 0; u < 4; ++u) {
        float4 o;
        o.x = acc[u][0] + bsv.x; o.y = acc[u][1] + bsv.y;
        o.z = acc[u][2] + bsv.z; o.w = acc[u][3] + bsv.w;
        *(float4*)(C + (size_t)(m0 + ty * 4 + u) * N + n0 + tx * 4) = o;
    }
}

// ---------------- one-time transpose: WT[c][j] = [W_hh|Ww_hh][j][c] (f32 out) ----------------
__global__ __launch_bounds__(256) void transpose_cat_kernel(
    const void* __restrict__ W_hh, const void* __restrict__ Ww_hh,
    const int* __restrict__ cnt, float* __restrict__ out)
{
    const int mode = (*cnt > NDET / 2) ? 1 : 0;
    __shared__ float tile[32][33];
    const int c0 = blockIdx.x * 32;   // [0,3072)
    const int j0 = blockIdx.y * 32;   // [0,512)
    const int tx = threadIdx.x & 31, ty = threadIdx.x >> 5;
    const void* src = (c0 < TH3) ? W_hh : Ww_hh;
    const int cc0 = (c0 < TH3) ? c0 : c0 - TH3;
    #pragma unroll
    for (int dy = 0; dy < 32; dy += 8)
        tile[ty + dy][tx] = ld1e(src, (size_t)(j0 + ty + dy) * TH3 + cc0 + tx, mode);
    __syncthreads();
    #pragma unroll
    for (int dy = 0; dy < 32; dy += 8)
        out[(size_t)(c0 + ty + dy) * HD + j0 + tx] = tile[tx][ty + dy];
}

// ---------------- flag-array barrier (init only) ----------------
__device__ inline void gbar(int* flags, int b, int k) {
    __atomic_signal_fence(__ATOMIC_SEQ_CST);
    __builtin_amdgcn_s_waitcnt(0);       // drain this wave's stores/atomics
    __syncthreads();                     // all waves drained
    if (threadIdx.x < 64) {
        if (threadIdx.x == 0) stg_a(&flags[b], k);
        for (;;) {
            int v = ldg_a(&flags[threadIdx.x]);
            if (__all(v >= k)) break;
            __builtin_amdgcn_s_sleep(1);
        }
    }
    __syncthreads();
    __atomic_signal_fence(__ATOMIC_SEQ_CST);
}

__device__ inline float wave_red(float acc) {
    #pragma unroll
    for (int m = 1; m < 64; m <<= 1) acc += __shfl_xor(acc, m, 64);
    return acc;
}

// ---------------- persistent scan: NO per-step barrier; sentinel-polled dataflow ----------------
__global__ __launch_bounds__(NT, 1) void lattice_scan(
    const float* WT, const void* __restrict__ Ww_hh,
    const void* __restrict__ aW_hh,
    const float* __restrict__ WIb, const float* __restrict__ AWIb,
    const float* __restrict__ WWIb,
    float* zw, int* zwCnt, float* hfull, float* cfull,
    float* c_buf, int* __restrict__ flags,
    const int* __restrict__ cnt,
    const int* __restrict__ gpos, const int* __restrict__ gslot,
    const unsigned char* __restrict__ gmaskb,
    int* __restrict__ meta_hdr, int* __restrict__ meta_rows,
    void* __restrict__ outp, int Km)
{
    __shared__ __align__(16) float Wa[HB][HD];       // own 8 cols of aW_hh (16 KB)
    __shared__ __align__(16) float cinS[MAXW][HD];   // staged cin rows (32 KB)
    __shared__ __align__(16) float zwFull[TH3];      // full word-z (len-2 steps)
    __shared__ __align__(16) float csFull[HD];       // full c_{t-1} (len-2 steps)
    __shared__ float zG[3][HB], wwOwn[KWW][3][HB], wiOwn[4][HB];
    __shared__ float hOwn[HB], cOwn[HB], wdot[MAXW][HB];
    __shared__ int mh_l[2], mr_l[2][MAXW];
    __shared__ int mfmt;

    const int b    = blockIdx.x;
    const int tid  = threadIdx.x;
    const int wid  = tid >> 6;
    const int q    = tid & 63;
    const int mode = (*cnt > NDET / 2) ? 1 : 0;
    const int hb0  = b * HB;          // first own h-channel

    // ---- one-time init: column-slice z weights into registers.
    // wave wid owns h-channel hb0+wid's 6 gate columns; lane q holds rows q+64i.
    float wreg[6][8];
    #pragma unroll
    for (int k = 0; k < 6; ++k)
        #pragma unroll
        for (int i = 0; i < 8; ++i)
            wreg[k][i] = WT[(size_t)(k * HD + hb0 + wid) * HD + q + 64 * i];
    // row-slice word-z weights (partial publication): thread owns cols {tid,512+tid,1024+tid}
    float wwreg[8][3];
    #pragma unroll
    for (int j = 0; j < 8; ++j)
        #pragma unroll
        for (int g = 0; g < 3; ++g)
            wwreg[j][g] = ld1e(Ww_hh, (size_t)(hb0 + j) * TH3 + g * HD + tid, mode);
    for (int idx = tid; idx < HB * HD; idx += NT) {
        int ho = idx & (HB - 1), r = idx / HB;
        Wa[ho][r] = ld1e(aW_hh, (size_t)r * HD + hb0 + ho, mode);
    }
    if (tid < HB) { hOwn[tid] = 0.f; cOwn[tid] = 0.f; }
    if (tid == 0) mfmt = 0;
    __syncthreads();
    {   // mask storage width: nonzero byte at i%4!=0 => u8/bool storage
        int any = 0;
        int tot = SEQ * Km;
        for (int i = tid; i < tot; i += NT)
            if ((i & 3) && gmaskb[i]) any = 1;
        if (any) mfmt = 1;
    }
    __syncthreads();
    const int maskfmt = mfmt;
    const int* gmi = (const int*)gmaskb;

    // ---- one-time metadata precompute: rows packed (p<<2)|sl ----
    if (tid < SPB) {
        int t = b * SPB + tid;
        int nv = 0;
        for (int k = 0; k < Km; ++k) {
            int mv = maskfmt ? (int)gmaskb[t * Km + k] : gmi[t * Km + k];
            if (!mv) continue;
            int p = gpos[t * Km + k], sl = gslot[t * Km + k];
            if (p < 0 || p >= t || sl < 0 || sl >= KWW) continue;
            if (nv < MAXW) { stg_a(&meta_rows[t * MAXW + nv], (p << 2) | sl); nv++; }
        }
        stg_a(&meta_hdr[t], nv);
    }
    gbar(flags, b, 1);   // publish metadata (only global barrier in the kernel)

    // meta for step 0 (plain loads: immutable after barrier)
    if (tid == 0) mh_l[0] = ldg_a(&meta_hdr[0]);
    if (tid < MAXW) mr_l[0][tid] = ldg_a(&meta_rows[tid]);
    __syncthreads();

    for (int t = 0; t < SEQ; ++t) {
        const int par = t & 1;
        const int nv = mh_l[par];
        // any len-2 word (created at t-1, consumed this step)?
        bool anyl2 = false;
        for (int vi = 0; vi < nv; ++vi)
            if ((mr_l[par][vi] >> 2) == t - 1) anyl2 = true;

        // ===== immutable per-step loads (issue early, overlap the polls) =====
        if (tid < 4 * HB) {
            int g = tid >> 3, ho = tid & (HB - 1);
            wiOwn[g][ho] = (g < 3) ? WIb[(size_t)t * TH3 + g * HD + hb0 + ho]
                                   : AWIb[(size_t)t * HD + hb0 + ho];
        }
        if (t > 0 && tid < KWW * 3 * HB) {
            int sl = tid / (3 * HB), g = (tid / HB) % 3, ho = tid & (HB - 1);
            wwOwn[sl][g][ho] =
                WWIb[(size_t)((t - 1) * KWW + sl) * TH3 + g * HD + hb0 + ho];
        }
        if (t + 1 < SEQ) {
            if (tid == 0) mh_l[par ^ 1] = ldg_a(&meta_hdr[t + 1]);
            if (tid < MAXW)
                mr_l[par ^ 1][tid] = ldg_a(&meta_rows[(size_t)(t + 1) * MAXW + tid]);
        }

        // ===== far cin rows -> cinS (sentinel-polled; c_buf rows write-once) =====
        {
            int g = tid >> 5, l = tid & 31;
            bool act = false;
            const unsigned int* src = nullptr;
            if (g < nv) {
                int e = mr_l[par][g], p = e >> 2, sl = e & 3;
                if (p <= t - 2)
                    { act = true; src = (const unsigned int*)(c_buf + (size_t)(p * KWW + sl) * HD); }
            }
            float v[16];
            for (;;) {
                bool ok = true;
                if (act) {
                    #pragma unroll
                    for (int i = 0; i < 16; ++i) {
                        unsigned int u = ldu_a(src + l + 32 * i);
                        v[i] = __builtin_bit_cast(float, u);
                        ok &= (u != SENT);
                    }
                }
                if (__all(ok)) break;
                __builtin_amdgcn_s_sleep(1);
            }
            if (act) {
                #pragma unroll
                for (int i = 0; i < 16; ++i) cinS[g][l + 32 * i] = v[i];
            }
        }

        // ===== h_{t-1}: poll the data itself straight into GEMV registers =====
        float hv[8];
        if (t > 0) {
            const unsigned int* hrow = (const unsigned int*)(hfull + (size_t)(t - 1) * HD);
            for (;;) {
                bool ok = true;
                #pragma unroll
                for (int i = 0; i < 8; ++i) {
                    unsigned int u = ldu_a(hrow + q + 64 * i);
                    hv[i] = __builtin_bit_cast(float, u);
                    ok &= (u != SENT);
                }
                if (__all(ok)) break;
                __builtin_amdgcn_s_sleep(1);
            }
        } else {
            #pragma unroll
            for (int i = 0; i < 8; ++i) hv[i] = 0.f;
        }

        // ===== len-2 support: word-z via arrival counter, c_{t-1} via sentinel =====
        if (anyl2) {
            while (ldg_a(&zwCnt[t - 1]) < GRID) __builtin_amdgcn_s_sleep(1);
            #pragma unroll
            for (int i = 0; i < 3; ++i)
                zwFull[tid + HD * i] = ldg_a(&zw[(size_t)(t - 1) * TH3 + tid + HD * i]);
            const unsigned int* crow = (const unsigned int*)(cfull + (size_t)(t - 1) * HD);
            for (;;) {
                unsigned int u = ldu_a(crow + tid);
                if (__all(u != SENT)) { csFull[tid] = __builtin_bit_cast(float, u); break; }
                __builtin_amdgcn_s_sleep(1);
            }
        }
        __syncthreads();

        // ===== column-local z GEMV + cells born at t-1 (per-wave, in-register) =====
        {
            float zk[6];
            #pragma unroll
            for (int k = 0; k < 6; ++k) {
                float a = 0.f;
                #pragma unroll
                for (int i = 0; i < 8; ++i) a = fmaf(hv[i], wreg[k][i], a);
                zk[k] = wave_red(a);
            }
            if (q == 0) {
                zG[0][wid] = zk[0]; zG[1][wid] = zk[1]; zG[2][wid] = zk[2];
            }
            if (t > 0 && q < KWW) {
                float cv = sigf(wwOwn[q][0][wid] + zk[3]) * cOwn[wid]
                         + sigf(wwOwn[q][1][wid] + zk[4])
                           * tanhf(wwOwn[q][2][wid] + zk[5]);
                stg_a(&c_buf[(size_t)((t - 1) * KWW + q) * HD + hb0 + wid], cv);
            }
        }
        // ===== len-2 recompute: full cell into cinS[vi] =====
        if (anyl2) {
            for (int vi = 0; vi < nv; ++vi) {
                int e = mr_l[par][vi], p = e >> 2, sl = e & 3;
                if (p != t - 1) continue;
                const float* wrow = WWIb + (size_t)((t - 1) * KWW + sl) * TH3;
                cinS[vi][tid] = sigf(wrow[tid] + zwFull[tid]) * csFull[tid]
                              + sigf(wrow[HD + tid] + zwFull[HD + tid])
                                * tanhf(wrow[2 * HD + tid] + zwFull[2 * HD + tid]);
            }
        }
        __syncthreads();

        // ===== alpha dots: nv*8 wave-jobs, stride-64 conflict-free =====
        if (nv > 0) {
            for (int jj = wid; jj < nv * HB; jj += 8) {
                int vi = jj >> 3, ho = jj & (HB - 1);
                float acc = 0.f;
                #pragma unroll
                for (int i = 0; i < 8; ++i)
                    acc += cinS[vi][q + 64 * i] * Wa[ho][q + 64 * i];
                acc = wave_red(acc);
                if (q == 0) wdot[vi][ho] = acc;
            }
        }
        __syncthreads();

        // ===== merge: own 8 channels; publish h/c (data IS the flag) =====
        if (tid < HB) {
            int ho = tid;
            float gi = sigf(zG[0][ho] + wiOwn[0][ho]);
            float go = sigf(zG[1][ho] + wiOwn[1][ho]);
            float gg = tanhf(zG[2][ho] + wiOwn[2][ho]);
            float c1;
            if (nv > 0) {
                float wiE = expf(gi);
                float num = wiE * gg, den = wiE;
                for (int vi = 0; vi < nv; ++vi) {
                    float wa = expf(sigf(wiOwn[3][ho] + wdot[vi][ho]));
                    num += wa * cinS[vi][hb0 + ho];
                    den += wa;
                }
                c1 = num / den;
            } else {
                c1 = (1.f - gi) * cOwn[ho] + gi * gg;
            }
            float h1 = go * tanhf(c1);
            cOwn[ho] = c1;
            hOwn[ho] = h1;
            stg_a(&hfull[(size_t)t * HD + hb0 + ho], h1);
            stg_a(&cfull[(size_t)t * HD + hb0 + ho], c1);
            if (mode) {
                unsigned short* o = (unsigned short*)outp;
                o[(size_t)t * HD + hb0 + ho] = f2bf(h1);
                o[(size_t)SEQ * HD + (size_t)t * HD + hb0 + ho] = f2bf(c1);
            } else {
                float* o = (float*)outp;
                o[(size_t)t * HD + hb0 + ho] = h1;
                o[(size_t)SEQ * HD + (size_t)t * HD + hb0 + ho] = c1;
            }
        }
        __syncthreads();

        // ===== publish word-z partials ONLY if next step consumes a len-2 word =====
        bool anyl2n = false;
        if (t + 1 < SEQ) {
            int nvn = mh_l[par ^ 1];
            for (int vi = 0; vi < nvn; ++vi)
                if ((mr_l[par ^ 1][vi] >> 2) == t) anyl2n = true;
        }
        if (anyl2n) {
            float h8[8];
            #pragma unroll
            for (int j = 0; j < 8; ++j) h8[j] = hOwn[j];
            #pragma unroll
            for (int g2 = 0; g2 < 3; ++g2) {
                float p = 0.f;
                #pragma unroll
                for (int j = 0; j < 8; ++j) p = fmaf(h8[j], wwreg[j][g2], p);
                atomicAdd(&zw[(size_t)t * TH3 + g2 * HD + tid], p);
            }
            __builtin_amdgcn_s_waitcnt(0);   // own adds performed at LLC
            __syncthreads();                 // all waves drained
            if (tid == 0) atomicAdd(&zwCnt[t], 1);
        }
        // no barrier: next step's polls enforce the dependency
    }
}

extern "C" void kernel_launch(void* const* d_in, const int* in_sizes, int n_in,
                              void* d_out, int out_size, void* d_ws, size_t ws_size,
                              hipStream_t stream) {
    const void* x     = d_in[0];
    const void* W_ih  = d_in[1];
    const void* W_hh  = d_in[2];
    const void* bb    = d_in[3];
    const void* aW_ih = d_in[4];
    const void* aW_hh = d_in[5];
    const void* ab    = d_in[6];
    const void* Ww_ih = d_in[7];
    const void* Ww_hh = d_in[8];
    const void* bw    = d_in[9];
    const void* wemb  = d_in[10];
    const int* wids  = (const int*)d_in[11];
    const int* gpos  = (const int*)d_in[12];
    const int* gslot = (const int*)d_in[13];
    const unsigned char* gmask = (const unsigned char*)d_in[14];

    int Km = in_sizes[12] / SEQ;
    if (Km > 32) Km = 32;
    if (ws_size < WS_END) return;

    char* ws = (char*)d_ws;
    int*   flags = (int*)(ws + WS_FLAGS);
    int*   cnt   = (int*)(ws + WS_CNT);
    int*   zwCnt = (int*)(ws + WS_ZWCNT);
    float* zw    = (float*)(ws + WS_ZW);
    float* c_buf = (float*)(ws + WS_CBUF);
    float* hfull = (float*)(ws + WS_HFULL);
    float* cfull = (float*)(ws + WS_CFULL);
    int*   mhdr  = (int*)(ws + WS_MHDR);
    int*   mrows = (int*)(ws + WS_MROWS);
    float* WIb   = (float*)(ws + WS_WIB);
    float* AWIb  = (float*)(ws + WS_AWIB);
    float* WWIb  = (float*)(ws + WS_WWIB);
    float* WT    = (float*)(ws + WS_WT);

    hipMemsetAsync(ws, 0, WS_ZEROSZ, stream);                         // flags/cnt/zwCnt/zw
    hipMemsetAsync(ws + WS_CBUF, 0xFF, WS_FFEND - WS_CBUF, stream);   // sentinel buffers
    detect_kernel<<<1, 256, 0, stream>>>((const unsigned int*)W_ih, cnt);
    transpose_cat_kernel<<<dim3(ZT / 32, HD / 32), 256, 0, stream>>>(
        W_hh, Ww_hh, cnt, WT);
    gemm_bias_kernel<false><<<dim3(TH3 / 64, SEQ / 64), 256, 0, stream>>>(
        x, W_ih, bb, nullptr, cnt, WIb, SEQ, TH3, HD);
    gemm_bias_kernel<false><<<dim3(HD / 64, SEQ / 64), 256, 0, stream>>>(
        x, aW_ih, ab, nullptr, cnt, AWIb, SEQ, HD, HD);
    gemm_bias_kernel<true><<<dim3(TH3 / 64, (SEQ * KWW) / 64), 256, 0, stream>>>(
        wemb, Ww_ih, bw, wids, cnt, WWIb, SEQ * KWW, TH3, HD);
    lattice_scan<<<GRID, NT, 0, stream>>>(
        WT, Ww_hh, aW_hh, WIb, AWIb, WWIb,
        zw, zwCnt, hfull, cfull, c_buf, flags, cnt,
        gpos, gslot, gmask, mhdr, mrows, d_out, Km);
}

// Round 3
// 9524.004 us; speedup vs baseline: 1.6787x; 1.1160x over previous
//
#include <hip/hip_runtime.h>

// ---------------- problem constants ----------------
constexpr int SEQ = 2048;
constexpr int HD  = 512;     // H = D = DW
constexpr int TH3 = 1536;    // 3H
constexpr int ZT  = 3072;    // combined [W_hh | Ww_hh] output cols
constexpr int KWW = 3;

constexpr int GRID = 64;     // scan blocks
constexpr int NT   = 512;    // threads/block (8 waves)
constexpr int HB   = HD / GRID;   // 8 h-channels per block (1 per wave)
constexpr int SPB  = SEQ / GRID;  // 32 steps/block metadata precompute
constexpr int MAXW = 16;

constexpr unsigned int SENT = 0xFFFFFFFFu;   // NaN pattern, unreachable by finite gate math

// ws layout (bytes)
// -- zero-memset region --
constexpr size_t WS_FLAGS  = 0;                         // 64 ints (init barrier only)
constexpr size_t WS_CNT    = 1024;                      // dtype-detect counter
constexpr size_t WS_ZEROSZ = 2048;
// -- 0xFF-memset region (sentinel-polled buffers) --
constexpr size_t WS_CBUF   = 2048;                               // SEQ*KWW*HD f32
constexpr size_t WS_HFULL  = WS_CBUF + (size_t)SEQ*KWW*HD*4;     // SEQ*HD f32 (h_t rows)
constexpr size_t WS_FFEND  = WS_HFULL + (size_t)SEQ*HD*4;
// -- plain region --
constexpr size_t WS_MHDR   = ((WS_FFEND + 255)/256)*256;         // SEQ i32
constexpr size_t WS_MROWS  = WS_MHDR + (size_t)SEQ*4;            // SEQ*MAXW i32
constexpr size_t WS_WIB    = WS_MROWS + (size_t)SEQ*MAXW*4;      // SEQ*1536 f32
constexpr size_t WS_AWIB   = WS_WIB  + (size_t)SEQ*TH3*4;        // SEQ*512 f32
constexpr size_t WS_WWIB   = WS_AWIB + (size_t)SEQ*HD*4;         // SEQ*KWW*1536 f32
constexpr size_t WS_WT     = WS_WWIB + (size_t)SEQ*KWW*TH3*4;    // 3072*512 f32 W^T
constexpr size_t WS_END    = WS_WT + (size_t)ZT*HD*4;

__device__ inline float bf2f(unsigned int u) {
    return __builtin_bit_cast(float, u << 16);
}
__device__ inline unsigned short f2bf(float f) {
    unsigned int u = __builtin_bit_cast(unsigned int, f);
    u += 0x7fffu + ((u >> 16) & 1u);   // RNE
    return (unsigned short)(u >> 16);
}
__device__ inline float sigf(float x) { return 1.0f / (1.0f + expf(-x)); }

// LLC-coherent (agent-scope relaxed) accesses: bypass non-coherent L1/L2.
template <typename T>
__device__ inline T ldg_a(const T* p) {
    return __hip_atomic_load((T*)p, __ATOMIC_RELAXED, __HIP_MEMORY_SCOPE_AGENT);
}
template <typename T>
__device__ inline void stg_a(T* p, T v) {
    __hip_atomic_store(p, v, __ATOMIC_RELAXED, __HIP_MEMORY_SCOPE_AGENT);
}
__device__ inline unsigned int ldu_a(const unsigned int* p) {
    return __hip_atomic_load((unsigned int*)p, __ATOMIC_RELAXED, __HIP_MEMORY_SCOPE_AGENT);
}

// dual-dtype loads: mode=1 -> bf16 storage, mode=0 -> f32 storage
__device__ inline float4 ld4e(const void* p, size_t eoff, int mode) {
    if (mode) {
        uint2 v = *(const uint2*)((const unsigned short*)p + eoff);
        return make_float4(bf2f(v.x & 0xffffu), bf2f(v.x >> 16),
                           bf2f(v.y & 0xffffu), bf2f(v.y >> 16));
    }
    return *(const float4*)((const float*)p + eoff);
}
__device__ inline float ld1e(const void* p, size_t eoff, int mode) {
    return mode ? bf2f((unsigned int)((const unsigned short*)p)[eoff])
                : ((const float*)p)[eoff];
}

// ---------------- dtype detection ----------------
constexpr int NDET = 4096;
__global__ void detect_kernel(const unsigned int* __restrict__ w, int* __restrict__ cnt) {
    int local = 0;
    for (int i = threadIdx.x; i < NDET; i += 256) {
        unsigned int e = (w[i] >> 7) & 0xffu;
        if (e >= 90u && e <= 140u) local++;
    }
    atomicAdd(cnt, local);
}

// ---------------- precompute GEMM: C[M,N] = gather(A)[M,K] @ B[K,N] + bias ----------------
template<bool GATHER>
__global__ __launch_bounds__(256) void gemm_bias_kernel(
    const void* __restrict__ A, const void* __restrict__ B,
    const void* __restrict__ bias, const int* __restrict__ ids,
    const int* __restrict__ cnt,
    float* __restrict__ C, int M, int N, int K)
{
    const int mode = (*cnt > NDET / 2) ? 1 : 0;
    __shared__ __align__(16) float As[16][68];
    __shared__ __align__(16) float Bs[16][68];
    const int tid = threadIdx.x;
    const int ty = tid >> 4, tx = tid & 15;
    const int m0 = blockIdx.y * 64, n0 = blockIdx.x * 64;
    const int lrow = tid >> 2;
    const int kq   = (tid & 3) * 4;
    const int arow = m0 + lrow;
    const size_t abase = (GATHER ? (size_t)ids[arow] : (size_t)arow) * (size_t)K;
    const int brow = tid >> 4;
    const int bc   = (tid & 15) * 4;
    const int bcol = n0 + bc;
    float acc[4][4] = {};
    for (int k0 = 0; k0 < K; k0 += 16) {
        float4 av = ld4e(A, abase + k0 + kq, mode);
        float4 bv = ld4e(B, (size_t)(k0 + brow) * N + bcol, mode);
        As[kq + 0][lrow] = av.x;
        As[kq + 1][lrow] = av.y;
        As[kq + 2][lrow] = av.z;
        As[kq + 3][lrow] = av.w;
        Bs[brow][bc + 0] = bv.x;
        Bs[brow][bc + 1] = bv.y;
        Bs[brow][bc + 2] = bv.z;
        Bs[brow][bc + 3] = bv.w;
        __syncthreads();
        #pragma unroll
        for (int kk = 0; kk < 16; ++kk) {
            float a[4], bb[4];
            #pragma unroll
            for (int u = 0; u < 4; ++u) a[u] = As[kk][ty * 4 + u];
            #pragma unroll
            for (int v = 0; v < 4; ++v) bb[v] = Bs[kk][tx * 4 + v];
            #pragma unroll
            for (int u = 0; u < 4; ++u)
                #pragma unroll
                for (int v = 0; v < 4; ++v)
                    acc[u][v] = fmaf(a[u], bb[v], acc[u][v]);
        }
        __syncthreads();
    }
    float4 bsv = ld4e(bias, (size_t)(n0 + tx * 4), mode);
    #pragma unroll
    for (int u = 0; u < 4; ++u) {
        float4 o;
        o.x = acc[u][0] + bsv.x; o.y = acc[u][1] + bsv.y;
        o.z = acc[u][2] + bsv.z; o.w = acc[u][3] + bsv.w;
        *(float4*)(C + (size_t)(m0 + ty * 4 + u) * N + n0 + tx * 4) = o;
    }
}

// ---------------- one-time transpose: WT[c][j] = [W_hh|Ww_hh][j][c] (f32 out) ----------------
__global__ __launch_bounds__(256) void transpose_cat_kernel(
    const void* __restrict__ W_hh, const void* __restrict__ Ww_hh,
    const int* __restrict__ cnt, float* __restrict__ out)
{
    const int mode = (*cnt > NDET / 2) ? 1 : 0;
    __shared__ float tile[32][33];
    const int c0 = blockIdx.x * 32;   // [0,3072)
    const int j0 = blockIdx.y * 32;   // [0,512)
    const int tx = threadIdx.x & 31, ty = threadIdx.x >> 5;
    const void* src = (c0 < TH3) ? W_hh : Ww_hh;
    const int cc0 = (c0 < TH3) ? c0 : c0 - TH3;
    #pragma unroll
    for (int dy = 0; dy < 32; dy += 8)
        tile[ty + dy][tx] = ld1e(src, (size_t)(j0 + ty + dy) * TH3 + cc0 + tx, mode);
    __syncthreads();
    #pragma unroll
    for (int dy = 0; dy < 32; dy += 8)
        out[(size_t)(c0 + ty + dy) * HD + j0 + tx] = tile[tx][ty + dy];
}

// ---------------- flag-array barrier (init only) ----------------
__device__ inline void gbar(int* flags, int b, int k) {
    __atomic_signal_fence(__ATOMIC_SEQ_CST);
    __builtin_amdgcn_s_waitcnt(0);       // drain this wave's stores/atomics
    __syncthreads();                     // all waves drained
    if (threadIdx.x < 64) {
        if (threadIdx.x == 0) stg_a(&flags[b], k);
        for (;;) {
            int v = ldg_a(&flags[threadIdx.x]);
            if (__all(v >= k)) break;
            __builtin_amdgcn_s_sleep(1);
        }
    }
    __syncthreads();
    __atomic_signal_fence(__ATOMIC_SEQ_CST);
}

__device__ inline float wave_red(float acc) {
    #pragma unroll
    for (int m = 1; m < 64; m <<= 1) acc += __shfl_xor(acc, m, 64);
    return acc;
}

// ---------------- persistent scan: per-wave channel ownership, 1 sync/step ----------------
// Wave wid owns h-channel ch = b*8 + wid end-to-end: z-GEMV, born cells, alpha,
// merge (redundant on all 64 lanes; c_prev in registers), publish on lane 0.
// Cross-block sync is pure dataflow: sentinel polls on hfull / c_buf rows.
__global__ __launch_bounds__(NT, 1) void lattice_scan(
    const float* WT, const void* __restrict__ aW_hh,
    const float* __restrict__ WIb, const float* __restrict__ AWIb,
    const float* __restrict__ WWIb,
    float* hfull, float* c_buf, int* __restrict__ flags,
    const int* __restrict__ cnt,
    const int* __restrict__ gpos, const int* __restrict__ gslot,
    const unsigned char* __restrict__ gmaskb,
    int* __restrict__ meta_hdr, int* __restrict__ meta_rows,
    void* __restrict__ outp, int Km)
{
    __shared__ __align__(16) float cinS[2][MAXW][HD];   // double-buffered cin rows (64 KB)
    __shared__ int mh_l[2], mr_l[2][MAXW];
    __shared__ int mfmt;

    const int b    = blockIdx.x;
    const int tid  = threadIdx.x;
    const int wid  = tid >> 6;
    const int q    = tid & 63;
    const int mode = (*cnt > NDET / 2) ? 1 : 0;
    const int hb0  = b * HB;
    const int ch   = hb0 + wid;       // own h-channel (one per wave)

    // ---- one-time init: z weight columns for own channel (6 gates x 8 rows/lane) ----
    float wreg[6][8];
    #pragma unroll
    for (int k = 0; k < 6; ++k)
        #pragma unroll
        for (int i = 0; i < 8; ++i)
            wreg[k][i] = WT[(size_t)(k * HD + ch) * HD + q + 64 * i];
    // alpha weight column for own channel
    float aw[8];
    #pragma unroll
    for (int i = 0; i < 8; ++i)
        aw[i] = ld1e(aW_hh, (size_t)(q + 64 * i) * HD + ch, mode);

    if (tid == 0) mfmt = 0;
    __syncthreads();
    {   // mask storage width: nonzero byte at i%4!=0 => u8/bool storage
        int any = 0;
        int tot = SEQ * Km;
        for (int i = tid; i < tot; i += NT)
            if ((i & 3) && gmaskb[i]) any = 1;
        if (any) mfmt = 1;
    }
    __syncthreads();
    const int maskfmt = mfmt;
    const int* gmi = (const int*)gmaskb;

    // ---- one-time metadata precompute: rows packed (p<<2)|sl ----
    if (tid < SPB) {
        int t = b * SPB + tid;
        int nv = 0;
        for (int k = 0; k < Km; ++k) {
            int mv = maskfmt ? (int)gmaskb[t * Km + k] : gmi[t * Km + k];
            if (!mv) continue;
            int p = gpos[t * Km + k], sl = gslot[t * Km + k];
            if (p < 0 || p >= t || sl < 0 || sl >= KWW) continue;
            if (nv < MAXW) { stg_a(&meta_rows[t * MAXW + nv], (p << 2) | sl); nv++; }
        }
        stg_a(&meta_hdr[t], nv);
    }
    gbar(flags, b, 1);   // publish metadata (only global barrier in the kernel)

    // meta for step 0 (plain loads: immutable after barrier)
    if (tid == 0) mh_l[0] = ldg_a(&meta_hdr[0]);
    if (tid < MAXW) mr_l[0][tid] = ldg_a(&meta_rows[tid]);
    __syncthreads();

    float c_prev = 0.f;                 // own channel's c_{t-1}, live in all lanes

    for (int t = 0; t < SEQ; ++t) {
        const int par = t & 1;
        const int nv = mh_l[par];
        bool anyl2 = false;
        for (int vi = 0; vi < nv; ++vi)
            if ((mr_l[par][vi] >> 2) == t - 1) anyl2 = true;

        // ===== phase 1 =====
        // uniform immutable loads for own channel (broadcast addresses)
        float wi0 = WIb[(size_t)t * TH3 + ch];
        float wi1 = WIb[(size_t)t * TH3 + HD + ch];
        float wi2 = WIb[(size_t)t * TH3 + 2 * HD + ch];
        float wi3 = AWIb[(size_t)t * HD + ch];
        float wwf = 0.f, wwi = 0.f, wwg = 0.f;
        if (t > 0 && q < KWW) {
            const float* wr = WWIb + (size_t)((t - 1) * KWW + q) * TH3;
            wwf = wr[ch]; wwi = wr[HD + ch]; wwg = wr[2 * HD + ch];
        }
        // prefetch next meta
        if (t + 1 < SEQ) {
            if (tid == 0) mh_l[par ^ 1] = ldg_a(&meta_hdr[t + 1]);
            if (tid < MAXW)
                mr_l[par ^ 1][tid] = ldg_a(&meta_rows[(size_t)(t + 1) * MAXW + tid]);
        }

        // far cin rows (p <= t-2): sentinel-poll into cinS[par]
        {
            int g = tid >> 5, l = tid & 31;
            bool act = false;
            const unsigned int* src = nullptr;
            if (g < nv) {
                int e = mr_l[par][g], p = e >> 2, sl = e & 3;
                if (p <= t - 2)
                    { act = true; src = (const unsigned int*)(c_buf + (size_t)(p * KWW + sl) * HD); }
            }
            float v[16];
            for (;;) {
                bool ok = true;
                if (act) {
                    #pragma unroll
                    for (int i = 0; i < 16; ++i) {
                        unsigned int u = ldu_a(src + l + 32 * i);
                        v[i] = __builtin_bit_cast(float, u);
                        ok &= (u != SENT);
                    }
                }
                if (__all(ok)) break;
                __builtin_amdgcn_s_sleep(1);
            }
            if (act) {
                #pragma unroll
                for (int i = 0; i < 16; ++i) cinS[par][g][l + 32 * i] = v[i];
            }
        }

        // h_{t-1}: poll the data itself straight into GEMV registers
        float hv[8];
        if (t > 0) {
            const unsigned int* hrow = (const unsigned int*)(hfull + (size_t)(t - 1) * HD);
            for (;;) {
                bool ok = true;
                #pragma unroll
                for (int i = 0; i < 8; ++i) {
                    unsigned int u = ldu_a(hrow + q + 64 * i);
                    hv[i] = __builtin_bit_cast(float, u);
                    ok &= (u != SENT);
                }
                if (__all(ok)) break;
                __builtin_amdgcn_s_sleep(1);
            }
        } else {
            #pragma unroll
            for (int i = 0; i < 8; ++i) hv[i] = 0.f;
        }

        // z GEMV for own channel: 6 gate columns
        float zk[6];
        #pragma unroll
        for (int k = 0; k < 6; ++k) {
            float a = 0.f;
            #pragma unroll
            for (int i = 0; i < 8; ++i) a = fmaf(hv[i], wreg[k][i], a);
            zk[k] = wave_red(a);
        }

        // born cells (start t-1): own channel, all 3 slots, column-local — no reduction
        if (t > 0 && q < KWW) {
            float cv = sigf(wwf + zk[3]) * c_prev
                     + sigf(wwi + zk[4]) * tanhf(wwg + zk[5]);
            stg_a(&c_buf[(size_t)((t - 1) * KWW + q) * HD + ch], cv);
        }

        // near cin rows (p == t-1, len-2 words): poll born stores of all blocks
        if (anyl2) {
            int g = tid >> 5, l = tid & 31;
            bool act = false;
            const unsigned int* src = nullptr;
            if (g < nv) {
                int e = mr_l[par][g], p = e >> 2, sl = e & 3;
                if (p == t - 1)
                    { act = true; src = (const unsigned int*)(c_buf + (size_t)(p * KWW + sl) * HD); }
            }
            float v[16];
            for (;;) {
                bool ok = true;
                if (act) {
                    #pragma unroll
                    for (int i = 0; i < 16; ++i) {
                        unsigned int u = ldu_a(src + l + 32 * i);
                        v[i] = __builtin_bit_cast(float, u);
                        ok &= (u != SENT);
                    }
                }
                if (__all(ok)) break;
                __builtin_amdgcn_s_sleep(1);
            }
            if (act) {
                #pragma unroll
                for (int i = 0; i < 16; ++i) cinS[par][g][l + 32 * i] = v[i];
            }
        }

        __syncthreads();   // cinS[par] complete; the ONLY in-block sync per step

        // ===== phase 2: alpha + merge, redundant on all lanes of own wave =====
        float gi = sigf(zk[0] + wi0);
        float go = sigf(zk[1] + wi1);
        float gg = tanhf(zk[2] + wi2);
        float c1;
        if (nv > 0) {
            float wiE = expf(gi);
            float num = wiE * gg, den = wiE;
            for (int vi = 0; vi < nv; ++vi) {
                float acc = 0.f;
                #pragma unroll
                for (int i = 0; i < 8; ++i)
                    acc += cinS[par][vi][q + 64 * i] * aw[i];
                acc = wave_red(acc);
                float wa = expf(sigf(wi3 + acc));
                num += wa * cinS[par][vi][ch];     // broadcast LDS read
                den += wa;
            }
            c1 = num / den;
        } else {
            c1 = (1.f - gi) * c_prev + gi * gg;
        }
        float h1 = go * tanhf(c1);
        c_prev = c1;
        if (q == 0) {
            stg_a(&hfull[(size_t)t * HD + ch], h1);
            if (mode) {
                unsigned short* o = (unsigned short*)outp;
                o[(size_t)t * HD + ch] = f2bf(h1);
                o[(size_t)SEQ * HD + (size_t)t * HD + ch] = f2bf(c1);
            } else {
                float* o = (float*)outp;
                o[(size_t)t * HD + ch] = h1;
                o[(size_t)SEQ * HD + (size_t)t * HD + ch] = c1;
            }
        }
        // no end-of-step sync: next step's polls + double-buffered cinS enforce order
    }
}

extern "C" void kernel_launch(void* const* d_in, const int* in_sizes, int n_in,
                              void* d_out, int out_size, void* d_ws, size_t ws_size,
                              hipStream_t stream) {
    const void* x     = d_in[0];
    const void* W_ih  = d_in[1];
    const void* W_hh  = d_in[2];
    const void* bb    = d_in[3];
    const void* aW_ih = d_in[4];
    const void* aW_hh = d_in[5];
    const void* ab    = d_in[6];
    const void* Ww_ih = d_in[7];
    const void* Ww_hh = d_in[8];
    const void* bw    = d_in[9];
    const void* wemb  = d_in[10];
    const int* wids  = (const int*)d_in[11];
    const int* gpos  = (const int*)d_in[12];
    const int* gslot = (const int*)d_in[13];
    const unsigned char* gmask = (const unsigned char*)d_in[14];

    int Km = in_sizes[12] / SEQ;
    if (Km > 32) Km = 32;
    if (ws_size < WS_END) return;

    char* ws = (char*)d_ws;
    int*   flags = (int*)(ws + WS_FLAGS);
    int*   cnt   = (int*)(ws + WS_CNT);
    float* c_buf = (float*)(ws + WS_CBUF);
    float* hfull = (float*)(ws + WS_HFULL);
    int*   mhdr  = (int*)(ws + WS_MHDR);
    int*   mrows = (int*)(ws + WS_MROWS);
    float* WIb   = (float*)(ws + WS_WIB);
    float* AWIb  = (float*)(ws + WS_AWIB);
    float* WWIb  = (float*)(ws + WS_WWIB);
    float* WT    = (float*)(ws + WS_WT);

    hipMemsetAsync(ws, 0, WS_ZEROSZ, stream);                         // flags/cnt
    hipMemsetAsync(ws + WS_CBUF, 0xFF, WS_FFEND - WS_CBUF, stream);   // sentinel buffers
    detect_kernel<<<1, 256, 0, stream>>>((const unsigned int*)W_ih, cnt);
    transpose_cat_kernel<<<dim3(ZT / 32, HD / 32), 256, 0, stream>>>(
        W_hh, Ww_hh, cnt, WT);
    gemm_bias_kernel<false><<<dim3(TH3 / 64, SEQ / 64), 256, 0, stream>>>(
        x, W_ih, bb, nullptr, cnt, WIb, SEQ, TH3, HD);
    gemm_bias_kernel<false><<<dim3(HD / 64, SEQ / 64), 256, 0, stream>>>(
        x, aW_ih, ab, nullptr, cnt, AWIb, SEQ, HD, HD);
    gemm_bias_kernel<true><<<dim3(TH3 / 64, (SEQ * KWW) / 64), 256, 0, stream>>>(
        wemb, Ww_ih, bw, wids, cnt, WWIb, SEQ * KWW, TH3, HD);
    lattice_scan<<<GRID, NT, 0, stream>>>(
        WT, aW_hh, WIb, AWIb, WWIb,
        hfull, c_buf, flags, cnt,
        gpos, gslot, gmask, mhdr, mrows, d_out, Km);
}